// Round 3
// baseline (9095.754 us; speedup 1.0000x reference)
//
#include <hip/hip_runtime.h>
#include <math.h>

#define B_N   32
#define T_N   1024
#define INDIM 60
#define DM_   256
#define L_N   4
#define DS_   32
#define DC_   4
#define DI_   512
#define DTR_  16
#define NTOK  (B_N * T_N)   // 32768

__device__ __forceinline__ float softplus_f(float x) {
    return x > 20.f ? x : log1pf(__expf(x));
}
__device__ __forceinline__ float silu_f(float x) {
    return x / (1.f + __expf(-x));
}

// ---------------------------------------------------------------------------
// Generic f32 GEMM:  C[M,N] = act(A[M,K] (row stride lda) * W[N,K]^T + bias)
// optionally accumulating into C. 64x64 tile, BK=16, 256 threads, 4x4/thread.
// ---------------------------------------------------------------------------
template<int HAS_BIAS, int ACT_SOFTPLUS, int ACCUM>
__global__ __launch_bounds__(256) void gemm_bt_kernel(
    const float* __restrict__ A, int lda,
    const float* __restrict__ W,
    const float* __restrict__ bias,
    float* __restrict__ C, int ldc,
    int N, int K)
{
    __shared__ float As[16][68];   // [k][m]
    __shared__ float Ws[16][68];   // [k][n]
    const int tid = threadIdx.x;
    const int tx = tid & 15, ty = tid >> 4;
    const int m0 = blockIdx.x * 64;
    const int n0 = blockIdx.y * 64;
    const int li = tid >> 2;          // 0..63 row within tile
    const int lj = (tid & 3) << 2;    // 0,4,8,12 k-offset

    float acc[4][4] = {};

    for (int k0 = 0; k0 < K; k0 += 16) {
        const int gk = k0 + lj;
        {
            const float* src = A + (size_t)(m0 + li) * lda + gk;
            float4 v;
            if (gk + 3 < K) {
                v = *(const float4*)src;
            } else {
                v.x = (gk + 0 < K) ? src[0] : 0.f;
                v.y = (gk + 1 < K) ? src[1] : 0.f;
                v.z = (gk + 2 < K) ? src[2] : 0.f;
                v.w = (gk + 3 < K) ? src[3] : 0.f;
            }
            As[lj + 0][li] = v.x; As[lj + 1][li] = v.y;
            As[lj + 2][li] = v.z; As[lj + 3][li] = v.w;
        }
        {
            const int gn = n0 + li;
            float4 v = make_float4(0.f, 0.f, 0.f, 0.f);
            if (gn < N) {
                const float* src = W + (size_t)gn * K + gk;
                if (gk + 3 < K) {
                    v = *(const float4*)src;
                } else {
                    v.x = (gk + 0 < K) ? src[0] : 0.f;
                    v.y = (gk + 1 < K) ? src[1] : 0.f;
                    v.z = (gk + 2 < K) ? src[2] : 0.f;
                    v.w = (gk + 3 < K) ? src[3] : 0.f;
                }
            }
            Ws[lj + 0][li] = v.x; Ws[lj + 1][li] = v.y;
            Ws[lj + 2][li] = v.z; Ws[lj + 3][li] = v.w;
        }
        __syncthreads();
        #pragma unroll
        for (int k = 0; k < 16; ++k) {
            float a0 = As[k][ty * 4 + 0], a1 = As[k][ty * 4 + 1];
            float a2 = As[k][ty * 4 + 2], a3 = As[k][ty * 4 + 3];
            float b0 = Ws[k][tx * 4 + 0], b1 = Ws[k][tx * 4 + 1];
            float b2 = Ws[k][tx * 4 + 2], b3 = Ws[k][tx * 4 + 3];
            acc[0][0] += a0 * b0; acc[0][1] += a0 * b1; acc[0][2] += a0 * b2; acc[0][3] += a0 * b3;
            acc[1][0] += a1 * b0; acc[1][1] += a1 * b1; acc[1][2] += a1 * b2; acc[1][3] += a1 * b3;
            acc[2][0] += a2 * b0; acc[2][1] += a2 * b1; acc[2][2] += a2 * b2; acc[2][3] += a2 * b3;
            acc[3][0] += a3 * b0; acc[3][1] += a3 * b1; acc[3][2] += a3 * b2; acc[3][3] += a3 * b3;
        }
        __syncthreads();
    }

    const int mb = m0 + ty * 4;
    const int nb = n0 + tx * 4;
    #pragma unroll
    for (int r = 0; r < 4; ++r) {
        float* dst = C + (size_t)(mb + r) * ldc + nb;
        if (nb + 3 < N) {
            float4 v = make_float4(acc[r][0], acc[r][1], acc[r][2], acc[r][3]);
            if (HAS_BIAS) {
                float4 bs = *(const float4*)(bias + nb);
                v.x += bs.x; v.y += bs.y; v.z += bs.z; v.w += bs.w;
            }
            if (ACT_SOFTPLUS) {
                v.x = softplus_f(v.x); v.y = softplus_f(v.y);
                v.z = softplus_f(v.z); v.w = softplus_f(v.w);
            }
            if (ACCUM) {
                float4 o = *(const float4*)dst;
                v.x += o.x; v.y += o.y; v.z += o.z; v.w += o.w;
            }
            *(float4*)dst = v;
        } else {
            #pragma unroll
            for (int c = 0; c < 4; ++c) {
                if (nb + c >= N) continue;
                float x = acc[r][c];
                if (HAS_BIAS) x += bias[nb + c];
                if (ACT_SOFTPLUS) x = softplus_f(x);
                if (ACCUM) x += dst[c];
                dst[c] = x;
            }
        }
    }
}

// ---------------------------------------------------------------------------
// LayerNorm(+bias,gamma) + ReLU over DM=256; one token per block.
// ---------------------------------------------------------------------------
__global__ __launch_bounds__(256) void ln_relu_kernel(
    const float* __restrict__ in, const float* __restrict__ g,
    const float* __restrict__ b, float* __restrict__ out)
{
    const int row = blockIdx.x;
    const int d = threadIdx.x;
    const float v = in[(size_t)row * DM_ + d];
    float s = v, s2 = v * v;
    #pragma unroll
    for (int off = 1; off < 64; off <<= 1) {
        s  += __shfl_xor(s, off);
        s2 += __shfl_xor(s2, off);
    }
    __shared__ float sm[8];
    const int wid = threadIdx.x >> 6, lane = threadIdx.x & 63;
    if (lane == 0) { sm[wid] = s; sm[4 + wid] = s2; }
    __syncthreads();
    s  = sm[0] + sm[1] + sm[2] + sm[3];
    s2 = sm[4] + sm[5] + sm[6] + sm[7];
    const float mean = s * (1.f / DM_);
    const float var  = s2 * (1.f / DM_) - mean * mean;
    const float o = (v - mean) * rsqrtf(var + 1e-5f) * g[d] + b[d];
    out[(size_t)row * DM_ + d] = fmaxf(o, 0.f);
}

// ---------------------------------------------------------------------------
// RMSNorm over DM=256; one token per block.
// ---------------------------------------------------------------------------
__global__ __launch_bounds__(256) void rmsnorm_kernel(
    const float* __restrict__ in, const float* __restrict__ g,
    float* __restrict__ out)
{
    const int row = blockIdx.x;
    const int d = threadIdx.x;
    const float v = in[(size_t)row * DM_ + d];
    float s2 = v * v;
    #pragma unroll
    for (int off = 1; off < 64; off <<= 1) s2 += __shfl_xor(s2, off);
    __shared__ float sm[4];
    const int wid = threadIdx.x >> 6, lane = threadIdx.x & 63;
    if (lane == 0) sm[wid] = s2;
    __syncthreads();
    s2 = sm[0] + sm[1] + sm[2] + sm[3];
    out[(size_t)row * DM_ + d] = v * rsqrtf(s2 * (1.f / DM_) + 1e-6f) * g[d];
}

// ---------------------------------------------------------------------------
// Causal depthwise conv (DC=4) over x_in (chunk-local, stride DI) + SiLU.
// ---------------------------------------------------------------------------
__global__ __launch_bounds__(256) void conv_silu_kernel(
    const float* __restrict__ xin, const float* __restrict__ cw,
    const float* __restrict__ cb, float* __restrict__ xc)
{
    const int idx = blockIdx.x * 256 + threadIdx.x;
    const int d  = idx & (DI_ - 1);
    const int bt = idx >> 9;
    const int t  = bt & (T_N - 1);   // chunks start at batch boundaries
    const float4 w = *(const float4*)(cw + d * 4);   // taps k=0..3
    const size_t base = (size_t)bt * DI_ + d;
    float acc = cb[d] + w.w * xin[base];             // k=3 -> t
    if (t >= 1) acc += w.z * xin[base - 1 * DI_];    // k=2 -> t-1
    if (t >= 2) acc += w.y * xin[base - 2 * DI_];    // k=1 -> t-2
    if (t >= 3) acc += w.x * xin[base - 3 * DI_];    // k=0 -> t-3
    xc[idx] = acc * (1.f / (1.f + __expf(-acc)));
}

// ---------------------------------------------------------------------------
// Selective scan v2: one thread per (b, d, s) — 1 state per thread.
// Block = 8 d-values x 32 s. Grid = nb * 64. 32 waves/CU at nb=32.
// y-reduce over the 32-lane s-group via shfl_xor; combine fused.
// ---------------------------------------------------------------------------
__global__ __launch_bounds__(256, 8) void scan_kernel2(
    const float* __restrict__ xdbl,    // (nb,T,80): dt|B|C
    const float* __restrict__ dlt,     // (nb,T,DI) precomputed softplus-delta
    const float* __restrict__ xc,      // (nb,T,DI)
    const float* __restrict__ z,       // (nb,T,DI)
    const float* __restrict__ alog,    // (DI,DS)
    const float* __restrict__ dskip,   // (DI)
    const float* __restrict__ alpha_p,
    const float* __restrict__ beta_p,
    float* __restrict__ y)             // (nb,T,DI)
{
    const int b  = blockIdx.x >> 6;
    const int g  = blockIdx.x & 63;
    const int dl = threadIdx.x >> 5;   // 0..7
    const int s  = threadIdx.x & 31;
    const int d  = g * 8 + dl;
    const float alpha = alpha_p[0];
    const float beta  = beta_p[0];
    const float na  = 1.f - alpha;
    const float dsk = dskip[d];
    const float A   = -__expf(alog[d * DS_ + s]);

    float hs = 0.f, vs = 0.f;
    size_t bt = (size_t)b * T_N;
    for (int t = 0; t < T_N; ++t, ++bt) {
        const float dv = dlt[bt * DI_ + d];
        const float xt = xc[bt * DI_ + d];
        const float Bv = xdbl[bt * 80 + 16 + s];
        const float Cv = xdbl[bt * 80 + 48 + s];
        const float dA  = __expf(dv * A);
        const float dBx = dv * xt * Bv;
        vs = beta * vs + dBx;
        hs = dA * hs + (alpha * vs + na * dBx);
        float ysum = hs * Cv;
        ysum += __shfl_xor(ysum, 1);
        ysum += __shfl_xor(ysum, 2);
        ysum += __shfl_xor(ysum, 4);
        ysum += __shfl_xor(ysum, 8);
        ysum += __shfl_xor(ysum, 16);
        if (s == 0) {
            const float zv = z[bt * DI_ + d];
            y[bt * DI_ + d] = (ysum + dsk * xt) * silu_f(zv);
        }
    }
}

// ---------------------------------------------------------------------------
extern "C" void kernel_launch(void* const* d_in, const int* in_sizes, int n_in,
                              void* d_out, int out_size, void* d_ws, size_t ws_size,
                              hipStream_t stream)
{
    const float* x     = (const float*)d_in[0];
    const float* fe_w  = (const float*)d_in[1];
    const float* fe_b  = (const float*)d_in[2];
    const float* ln_g  = (const float*)d_in[3];
    const float* ln_b  = (const float*)d_in[4];
    const float* bng   = (const float*)d_in[5];
    const float* inw   = (const float*)d_in[6];
    const float* convw = (const float*)d_in[7];
    const float* convb = (const float*)d_in[8];
    const float* xpw   = (const float*)d_in[9];
    const float* dtw   = (const float*)d_in[10];
    const float* dtb   = (const float*)d_in[11];
    const float* alog  = (const float*)d_in[12];
    const float* dskip = (const float*)d_in[13];
    const float* outw  = (const float*)d_in[14];
    const float* alpha = (const float*)d_in[15];
    const float* beta  = (const float*)d_in[16];
    const float* rmsg  = (const float*)d_in[17];

    // -------- workspace layout, adaptive to ws_size --------
    // h (B,T,DM) persistent + per-chunk: u (Mc,DM, also x_dbl) | x_in/y (Mc,DI)
    // | z (Mc,DI) | xc (Mc,DI) | dlt (Mc,DI)
    const size_t avail = ws_size / 4;  // floats
    int nb = 32;
    while (nb > 4 && 8388608ULL + (size_t)nb * 1024 * 2304 > avail) nb >>= 1;
    const int ntok_c = nb * 1024;

    float* ws   = (float*)d_ws;
    float* h    = ws;                                   // 8,388,608 f32
    float* u    = ws + 8388608;                         // ntok_c*256 (also x_dbl)
    float* xiny = u    + (size_t)ntok_c * 256;          // ntok_c*512 (x_in, then y)
    float* z    = xiny + (size_t)ntok_c * 512;          // ntok_c*512
    float* xc   = z    + (size_t)ntok_c * 512;          // ntok_c*512
    float* dl_  = xc   + (size_t)ntok_c * 512;          // ntok_c*512

    float* pre = (float*)d_out;  // pre-LN temp; fully rewritten at the end

    const dim3 blk(256);

    // feature extract: pre = x @ fe_w^T + fe_b
    gemm_bt_kernel<1,0,0><<<dim3(NTOK/64, DM_/64), blk, 0, stream>>>(
        x, INDIM, fe_w, fe_b, pre, DM_, DM_, INDIM);
    // h = relu(LN(pre))
    ln_relu_kernel<<<dim3(NTOK), blk, 0, stream>>>(pre, ln_g, ln_b, h);

    for (int l = 0; l < L_N; ++l) {
        const float* inw_l  = inw  + (size_t)l * 2 * DI_ * DM_;
        const float* xpw_l  = xpw  + (size_t)l * 80 * DI_;
        const float* dtw_l  = dtw  + (size_t)l * DI_ * DTR_;
        const float* outw_l = outw + (size_t)l * DM_ * DI_;

        for (int b0 = 0; b0 < B_N; b0 += nb) {
            float* h_c = h + (size_t)b0 * 1024 * DM_;
            // u = rmsnorm(h_c) * blk_norm_g[l]
            rmsnorm_kernel<<<dim3(ntok_c), blk, 0, stream>>>(h_c, bng + l * DM_, u);
            // x_in = u @ inw[0:DI]^T ; z = u @ inw[DI:2DI]^T
            gemm_bt_kernel<0,0,0><<<dim3(ntok_c/64, DI_/64), blk, 0, stream>>>(
                u, DM_, inw_l, nullptr, xiny, DI_, DI_, DM_);
            gemm_bt_kernel<0,0,0><<<dim3(ntok_c/64, DI_/64), blk, 0, stream>>>(
                u, DM_, inw_l + (size_t)DI_ * DM_, nullptr, z, DI_, DI_, DM_);
            // xc = silu(causal_conv(x_in) + cb)
            conv_silu_kernel<<<dim3((ntok_c * DI_) / 256), blk, 0, stream>>>(
                xiny, convw + l * DI_ * DC_, convb + l * DI_, xc);
            // x_dbl (overlays u) = xc @ x_proj_w[l]^T   (ntok_c,80)
            gemm_bt_kernel<0,0,0><<<dim3(ntok_c/64, 2), blk, 0, stream>>>(
                xc, DI_, xpw_l, nullptr, u, 80, 80, DI_);
            // delta = softplus(x_dbl[:, :16] @ dtw^T + dtb)
            gemm_bt_kernel<1,1,0><<<dim3(ntok_c/64, DI_/64), blk, 0, stream>>>(
                u, 80, dtw_l, dtb + l * DI_, dl_, DI_, DI_, DTR_);
            // scan -> y (overlays x_in)
            scan_kernel2<<<dim3(nb * 64), blk, 0, stream>>>(
                u, dl_, xc, z, alog + (size_t)l * DI_ * DS_,
                dskip + l * DI_, alpha + l, beta + l, xiny);
            // h_c += y @ out_proj_w[l]^T
            gemm_bt_kernel<0,0,1><<<dim3(ntok_c/64, DM_/64), blk, 0, stream>>>(
                xiny, DI_, outw_l, nullptr, h_c, DM_, DM_, DI_);
        }
    }

    // out = rmsnorm(h) * rms_g
    rmsnorm_kernel<<<dim3(NTOK), blk, 0, stream>>>(h, rmsg, (float*)d_out);
}

// Round 4
// 4671.593 us; speedup vs baseline: 1.9470x; 1.9470x over previous
//
#include <hip/hip_runtime.h>
#include <math.h>

#define B_N   32
#define T_N   1024
#define INDIM 60
#define DM_   256
#define L_N   4
#define DS_   32
#define DC_   4
#define DI_   512
#define DTR_  16
#define NTOK  (B_N * T_N)   // 32768
#define TC_   64            // timesteps per scan chunk
#define NC_   16            // chunks (T_N / TC_)

__device__ __forceinline__ float softplus_f(float x) {
    return x > 20.f ? x : log1pf(__expf(x));
}
__device__ __forceinline__ float silu_f(float x) {
    return x / (1.f + __expf(-x));
}

// ---------------------------------------------------------------------------
// Generic f32 GEMM:  C[M,N] = act(A[M,K] (row stride lda) * W[N,K]^T + bias)
// optionally accumulating into C. 64x64 tile, BK=16, 256 threads, 4x4/thread.
// ---------------------------------------------------------------------------
template<int HAS_BIAS, int ACT_SOFTPLUS, int ACCUM>
__global__ __launch_bounds__(256) void gemm_bt_kernel(
    const float* __restrict__ A, int lda,
    const float* __restrict__ W,
    const float* __restrict__ bias,
    float* __restrict__ C, int ldc,
    int N, int K)
{
    __shared__ float As[16][68];   // [k][m]
    __shared__ float Ws[16][68];   // [k][n]
    const int tid = threadIdx.x;
    const int tx = tid & 15, ty = tid >> 4;
    const int m0 = blockIdx.x * 64;
    const int n0 = blockIdx.y * 64;
    const int li = tid >> 2;          // 0..63 row within tile
    const int lj = (tid & 3) << 2;    // 0,4,8,12 k-offset

    float acc[4][4] = {};

    for (int k0 = 0; k0 < K; k0 += 16) {
        const int gk = k0 + lj;
        {
            const float* src = A + (size_t)(m0 + li) * lda + gk;
            float4 v;
            if (gk + 3 < K) {
                v = *(const float4*)src;
            } else {
                v.x = (gk + 0 < K) ? src[0] : 0.f;
                v.y = (gk + 1 < K) ? src[1] : 0.f;
                v.z = (gk + 2 < K) ? src[2] : 0.f;
                v.w = (gk + 3 < K) ? src[3] : 0.f;
            }
            As[lj + 0][li] = v.x; As[lj + 1][li] = v.y;
            As[lj + 2][li] = v.z; As[lj + 3][li] = v.w;
        }
        {
            const int gn = n0 + li;
            float4 v = make_float4(0.f, 0.f, 0.f, 0.f);
            if (gn < N) {
                const float* src = W + (size_t)gn * K + gk;
                if (gk + 3 < K) {
                    v = *(const float4*)src;
                } else {
                    v.x = (gk + 0 < K) ? src[0] : 0.f;
                    v.y = (gk + 1 < K) ? src[1] : 0.f;
                    v.z = (gk + 2 < K) ? src[2] : 0.f;
                    v.w = (gk + 3 < K) ? src[3] : 0.f;
                }
            }
            Ws[lj + 0][li] = v.x; Ws[lj + 1][li] = v.y;
            Ws[lj + 2][li] = v.z; Ws[lj + 3][li] = v.w;
        }
        __syncthreads();
        #pragma unroll
        for (int k = 0; k < 16; ++k) {
            float a0 = As[k][ty * 4 + 0], a1 = As[k][ty * 4 + 1];
            float a2 = As[k][ty * 4 + 2], a3 = As[k][ty * 4 + 3];
            float b0 = Ws[k][tx * 4 + 0], b1 = Ws[k][tx * 4 + 1];
            float b2 = Ws[k][tx * 4 + 2], b3 = Ws[k][tx * 4 + 3];
            acc[0][0] += a0 * b0; acc[0][1] += a0 * b1; acc[0][2] += a0 * b2; acc[0][3] += a0 * b3;
            acc[1][0] += a1 * b0; acc[1][1] += a1 * b1; acc[1][2] += a1 * b2; acc[1][3] += a1 * b3;
            acc[2][0] += a2 * b0; acc[2][1] += a2 * b1; acc[2][2] += a2 * b2; acc[2][3] += a2 * b3;
            acc[3][0] += a3 * b0; acc[3][1] += a3 * b1; acc[3][2] += a3 * b2; acc[3][3] += a3 * b3;
        }
        __syncthreads();
    }

    const int mb = m0 + ty * 4;
    const int nb = n0 + tx * 4;
    #pragma unroll
    for (int r = 0; r < 4; ++r) {
        float* dst = C + (size_t)(mb + r) * ldc + nb;
        if (nb + 3 < N) {
            float4 v = make_float4(acc[r][0], acc[r][1], acc[r][2], acc[r][3]);
            if (HAS_BIAS) {
                float4 bs = *(const float4*)(bias + nb);
                v.x += bs.x; v.y += bs.y; v.z += bs.z; v.w += bs.w;
            }
            if (ACT_SOFTPLUS) {
                v.x = softplus_f(v.x); v.y = softplus_f(v.y);
                v.z = softplus_f(v.z); v.w = softplus_f(v.w);
            }
            if (ACCUM) {
                float4 o = *(const float4*)dst;
                v.x += o.x; v.y += o.y; v.z += o.z; v.w += o.w;
            }
            *(float4*)dst = v;
        } else {
            #pragma unroll
            for (int c = 0; c < 4; ++c) {
                if (nb + c >= N) continue;
                float x = acc[r][c];
                if (HAS_BIAS) x += bias[nb + c];
                if (ACT_SOFTPLUS) x = softplus_f(x);
                if (ACCUM) x += dst[c];
                dst[c] = x;
            }
        }
    }
}

// ---------------------------------------------------------------------------
// LayerNorm(+bias,gamma) + ReLU over DM=256; one token per block.
// ---------------------------------------------------------------------------
__global__ __launch_bounds__(256) void ln_relu_kernel(
    const float* __restrict__ in, const float* __restrict__ g,
    const float* __restrict__ b, float* __restrict__ out)
{
    const int row = blockIdx.x;
    const int d = threadIdx.x;
    const float v = in[(size_t)row * DM_ + d];
    float s = v, s2 = v * v;
    #pragma unroll
    for (int off = 1; off < 64; off <<= 1) {
        s  += __shfl_xor(s, off);
        s2 += __shfl_xor(s2, off);
    }
    __shared__ float sm[8];
    const int wid = threadIdx.x >> 6, lane = threadIdx.x & 63;
    if (lane == 0) { sm[wid] = s; sm[4 + wid] = s2; }
    __syncthreads();
    s  = sm[0] + sm[1] + sm[2] + sm[3];
    s2 = sm[4] + sm[5] + sm[6] + sm[7];
    const float mean = s * (1.f / DM_);
    const float var  = s2 * (1.f / DM_) - mean * mean;
    const float o = (v - mean) * rsqrtf(var + 1e-5f) * g[d] + b[d];
    out[(size_t)row * DM_ + d] = fmaxf(o, 0.f);
}

// ---------------------------------------------------------------------------
// RMSNorm over DM=256; one token per block.
// ---------------------------------------------------------------------------
__global__ __launch_bounds__(256) void rmsnorm_kernel(
    const float* __restrict__ in, const float* __restrict__ g,
    float* __restrict__ out)
{
    const int row = blockIdx.x;
    const int d = threadIdx.x;
    const float v = in[(size_t)row * DM_ + d];
    float s2 = v * v;
    #pragma unroll
    for (int off = 1; off < 64; off <<= 1) s2 += __shfl_xor(s2, off);
    __shared__ float sm[4];
    const int wid = threadIdx.x >> 6, lane = threadIdx.x & 63;
    if (lane == 0) sm[wid] = s2;
    __syncthreads();
    s2 = sm[0] + sm[1] + sm[2] + sm[3];
    out[(size_t)row * DM_ + d] = v * rsqrtf(s2 * (1.f / DM_) + 1e-6f) * g[d];
}

// ---------------------------------------------------------------------------
// Causal depthwise conv (DC=4) over x_in (chunk-local, stride DI) + SiLU.
// ---------------------------------------------------------------------------
__global__ __launch_bounds__(256) void conv_silu_kernel(
    const float* __restrict__ xin, const float* __restrict__ cw,
    const float* __restrict__ cb, float* __restrict__ xc)
{
    const int idx = blockIdx.x * 256 + threadIdx.x;
    const int d  = idx & (DI_ - 1);
    const int bt = idx >> 9;
    const int t  = bt & (T_N - 1);   // chunks start at batch boundaries
    const float4 w = *(const float4*)(cw + d * 4);   // taps k=0..3
    const size_t base = (size_t)bt * DI_ + d;
    float acc = cb[d] + w.w * xin[base];             // k=3 -> t
    if (t >= 1) acc += w.z * xin[base - 1 * DI_];    // k=2 -> t-1
    if (t >= 2) acc += w.y * xin[base - 2 * DI_];    // k=1 -> t-2
    if (t >= 3) acc += w.x * xin[base - 3 * DI_];    // k=0 -> t-3
    xc[idx] = acc * (1.f / (1.f + __expf(-acc)));
}

// ---------------------------------------------------------------------------
// Chunk-parallel scan. State x=[h;v], x_t = M_t x_{t-1} + n_t with
//   M_t = [[dA_t, a*b],[0, b]], n_t = [dBx_t; dBx_t]
// (h_t = dA*h + a*b*v_{t-1} + dBx is algebraically identical to the ref.)
// Pass A: per (chunk, state) compute aggregate P=[[p11,p12],[0,b^TC]], q.
// Pass B: serial over NC_ chunks, propagate chunk-start states.
// Pass C: re-run each chunk from its true start state, emit y (+combine).
// Thread = (b, d, 8 s). Block = 64 d x 4 sg. Grid = (nb*8, NC_).
// ---------------------------------------------------------------------------
__global__ __launch_bounds__(256) void scan_passA(
    const float* __restrict__ xdbl,    // (nb,T,80): dt|B|C
    const float* __restrict__ dlt,     // (nb,T,DI)
    const float* __restrict__ xc,      // (nb,T,DI)
    const float* __restrict__ alog,    // (DI,DS)
    const float* __restrict__ alpha_p,
    const float* __restrict__ beta_p,
    float4* __restrict__ agg,          // (NC_, nstates)
    int nstates)
{
    const int b  = blockIdx.x >> 3;
    const int dg = blockIdx.x & 7;
    const int c  = blockIdx.y;
    const int dl = threadIdx.x >> 2;
    const int sg = threadIdx.x & 3;
    const int d  = dg * 64 + dl;
    const int s0 = sg * 8;
    const float alpha = alpha_p[0];
    const float beta  = beta_p[0];
    const float ab = alpha * beta;

    float A[8];
    #pragma unroll
    for (int j = 0; j < 8; ++j) A[j] = -__expf(alog[d * DS_ + s0 + j]);

    float p11[8], p12[8] = {}, q1[8] = {}, q2[8] = {};
    #pragma unroll
    for (int j = 0; j < 8; ++j) p11[j] = 1.f;
    float pw = 1.f;

    size_t bt = (size_t)b * T_N + (size_t)c * TC_;
    for (int k = 0; k < TC_; ++k, ++bt) {
        const float dv = dlt[bt * DI_ + d];
        const float xt = xc[bt * DI_ + d];
        const float dx = dv * xt;
        const float* row = xdbl + bt * 80;
        const float4 B0 = *(const float4*)(row + 16 + s0);
        const float4 B1 = *(const float4*)(row + 20 + s0);
        const float Bv[8] = {B0.x,B0.y,B0.z,B0.w,B1.x,B1.y,B1.z,B1.w};
        pw *= beta;
        const float apw = alpha * pw;
        #pragma unroll
        for (int j = 0; j < 8; ++j) {
            const float dA  = __expf(dv * A[j]);
            const float dBx = dx * Bv[j];
            q1[j]  = dA * q1[j] + ab * q2[j] + dBx;   // uses old q2
            q2[j]  = beta * q2[j] + dBx;
            p12[j] = dA * p12[j] + apw;
            p11[j] *= dA;
        }
    }
    const size_t sidb = ((size_t)b * DI_ + d) * DS_ + s0;
    #pragma unroll
    for (int j = 0; j < 8; ++j)
        agg[(size_t)c * nstates + sidb + j] =
            make_float4(p11[j], p12[j], q1[j], q2[j]);
}

__global__ __launch_bounds__(256) void scan_passB(
    const float4* __restrict__ agg, float2* __restrict__ st,
    const float* __restrict__ beta_p, int nstates)
{
    const int sid = blockIdx.x * 256 + threadIdx.x;
    if (sid >= nstates) return;
    float bTc = beta_p[0];
    #pragma unroll
    for (int i = 0; i < 6; ++i) bTc *= bTc;   // beta^64
    float h = 0.f, v = 0.f;
    for (int c = 0; c < NC_; ++c) {
        st[(size_t)c * nstates + sid] = make_float2(h, v);
        const float4 a = agg[(size_t)c * nstates + sid];
        const float hn = a.x * h + a.y * v + a.z;
        v = bTc * v + a.w;
        h = hn;
    }
}

__global__ __launch_bounds__(256) void scan_passC(
    const float* __restrict__ xdbl,
    const float* __restrict__ dlt,
    const float* __restrict__ xc,
    const float* __restrict__ z,
    const float2* __restrict__ st,
    const float* __restrict__ alog,
    const float* __restrict__ dskip,
    const float* __restrict__ alpha_p,
    const float* __restrict__ beta_p,
    float* __restrict__ y,
    int nstates)
{
    const int b  = blockIdx.x >> 3;
    const int dg = blockIdx.x & 7;
    const int c  = blockIdx.y;
    const int dl = threadIdx.x >> 2;
    const int sg = threadIdx.x & 3;
    const int d  = dg * 64 + dl;
    const int s0 = sg * 8;
    const float alpha = alpha_p[0];
    const float beta  = beta_p[0];
    const float na  = 1.f - alpha;
    const float dsk = dskip[d];

    float A[8];
    #pragma unroll
    for (int j = 0; j < 8; ++j) A[j] = -__expf(alog[d * DS_ + s0 + j]);

    const size_t sidb = ((size_t)b * DI_ + d) * DS_ + s0;
    float hs[8], vs[8];
    #pragma unroll
    for (int j = 0; j < 8; ++j) {
        const float2 s_ = st[(size_t)c * nstates + sidb + j];
        hs[j] = s_.x; vs[j] = s_.y;
    }

    size_t bt = (size_t)b * T_N + (size_t)c * TC_;
    for (int k = 0; k < TC_; ++k, ++bt) {
        const float dv = dlt[bt * DI_ + d];
        const float xt = xc[bt * DI_ + d];
        const float dx = dv * xt;
        const float* row = xdbl + bt * 80;
        const float4 B0 = *(const float4*)(row + 16 + s0);
        const float4 B1 = *(const float4*)(row + 20 + s0);
        const float4 C0 = *(const float4*)(row + 48 + s0);
        const float4 C1 = *(const float4*)(row + 52 + s0);
        const float Bv[8] = {B0.x,B0.y,B0.z,B0.w,B1.x,B1.y,B1.z,B1.w};
        const float Cv[8] = {C0.x,C0.y,C0.z,C0.w,C1.x,C1.y,C1.z,C1.w};
        float ysum = 0.f;
        #pragma unroll
        for (int j = 0; j < 8; ++j) {
            const float dA  = __expf(dv * A[j]);
            const float dBx = dx * Bv[j];
            vs[j] = beta * vs[j] + dBx;
            hs[j] = dA * hs[j] + (alpha * vs[j] + na * dBx);
            ysum += hs[j] * Cv[j];
        }
        ysum += __shfl_xor(ysum, 1);
        ysum += __shfl_xor(ysum, 2);
        if (sg == 0) {
            const float zv = z[bt * DI_ + d];
            y[bt * DI_ + d] = (ysum + dsk * xt) * silu_f(zv);
        }
    }
}

// ---------------------------------------------------------------------------
extern "C" void kernel_launch(void* const* d_in, const int* in_sizes, int n_in,
                              void* d_out, int out_size, void* d_ws, size_t ws_size,
                              hipStream_t stream)
{
    const float* x     = (const float*)d_in[0];
    const float* fe_w  = (const float*)d_in[1];
    const float* fe_b  = (const float*)d_in[2];
    const float* ln_g  = (const float*)d_in[3];
    const float* ln_b  = (const float*)d_in[4];
    const float* bng   = (const float*)d_in[5];
    const float* inw   = (const float*)d_in[6];
    const float* convw = (const float*)d_in[7];
    const float* convb = (const float*)d_in[8];
    const float* xpw   = (const float*)d_in[9];
    const float* dtw   = (const float*)d_in[10];
    const float* dtb   = (const float*)d_in[11];
    const float* alog  = (const float*)d_in[12];
    const float* dskip = (const float*)d_in[13];
    const float* outw  = (const float*)d_in[14];
    const float* alpha = (const float*)d_in[15];
    const float* beta  = (const float*)d_in[16];
    const float* rmsg  = (const float*)d_in[17];

    // h lives in d_out (B,T,DM). Workspace = per-batch-chunk buffers only.
    // Per b: tokens 1024*(256+512*4) = 2,359,296 fl; agg+st = 16384*NC_*6
    // = 1,572,864 fl  -> 3,932,160 fl (15.36 MiB). nb=16 -> 251.7 MiB.
    const size_t avail = ws_size / 4;  // floats
    int nb = 32;
    while (nb > 4 && (size_t)nb * 3932160ULL > avail) nb >>= 1;
    const int ntok_c  = nb * 1024;
    const int nstates = nb * DI_ * DS_ / 1;   // per-chunk-batch states

    float*  ws   = (float*)d_ws;
    float*  u    = ws;                                  // ntok_c*256 (also x_dbl)
    float*  xiny = u    + (size_t)ntok_c * 256;         // ntok_c*512 (x_in, then y)
    float*  z    = xiny + (size_t)ntok_c * 512;         // ntok_c*512
    float*  xc   = z    + (size_t)ntok_c * 512;         // ntok_c*512
    float*  dl_  = xc   + (size_t)ntok_c * 512;         // ntok_c*512
    float4* agg  = (float4*)(dl_ + (size_t)ntok_c * 512);        // nstates*NC_
    float2* st   = (float2*)((float*)agg + (size_t)nstates * NC_ * 4);

    float* h   = (float*)d_out;   // persistent hidden state (B,T,DM)
    float* pre = ws;              // pre-LN temp overlay (consumed immediately)

    const dim3 blk(256);

    // feature extract: pre = x @ fe_w^T + fe_b
    gemm_bt_kernel<1,0,0><<<dim3(NTOK/64, DM_/64), blk, 0, stream>>>(
        x, INDIM, fe_w, fe_b, pre, DM_, DM_, INDIM);
    // h = relu(LN(pre))
    ln_relu_kernel<<<dim3(NTOK), blk, 0, stream>>>(pre, ln_g, ln_b, h);

    for (int l = 0; l < L_N; ++l) {
        const float* inw_l  = inw  + (size_t)l * 2 * DI_ * DM_;
        const float* xpw_l  = xpw  + (size_t)l * 80 * DI_;
        const float* dtw_l  = dtw  + (size_t)l * DI_ * DTR_;
        const float* outw_l = outw + (size_t)l * DM_ * DI_;

        for (int b0 = 0; b0 < B_N; b0 += nb) {
            float* h_c = h + (size_t)b0 * 1024 * DM_;
            // u = rmsnorm(h_c) * blk_norm_g[l]
            rmsnorm_kernel<<<dim3(ntok_c), blk, 0, stream>>>(h_c, bng + l * DM_, u);
            // x_in = u @ inw[0:DI]^T ; z = u @ inw[DI:2DI]^T
            gemm_bt_kernel<0,0,0><<<dim3(ntok_c/64, DI_/64), blk, 0, stream>>>(
                u, DM_, inw_l, nullptr, xiny, DI_, DI_, DM_);
            gemm_bt_kernel<0,0,0><<<dim3(ntok_c/64, DI_/64), blk, 0, stream>>>(
                u, DM_, inw_l + (size_t)DI_ * DM_, nullptr, z, DI_, DI_, DM_);
            // xc = silu(causal_conv(x_in) + cb)
            conv_silu_kernel<<<dim3((ntok_c * DI_) / 256), blk, 0, stream>>>(
                xiny, convw + l * DI_ * DC_, convb + l * DI_, xc);
            // x_dbl (overlays u) = xc @ x_proj_w[l]^T   (ntok_c,80)
            gemm_bt_kernel<0,0,0><<<dim3(ntok_c/64, 2), blk, 0, stream>>>(
                xc, DI_, xpw_l, nullptr, u, 80, 80, DI_);
            // delta = softplus(x_dbl[:, :16] @ dtw^T + dtb)
            gemm_bt_kernel<1,1,0><<<dim3(ntok_c/64, DI_/64), blk, 0, stream>>>(
                u, 80, dtw_l, dtb + l * DI_, dl_, DI_, DI_, DTR_);
            // chunk-parallel scan
            scan_passA<<<dim3(nb * 8, NC_), blk, 0, stream>>>(
                u, dl_, xc, alog + (size_t)l * DI_ * DS_, alpha + l, beta + l,
                agg, nstates);
            scan_passB<<<dim3((nstates + 255) / 256), blk, 0, stream>>>(
                agg, st, beta + l, nstates);
            scan_passC<<<dim3(nb * 8, NC_), blk, 0, stream>>>(
                u, dl_, xc, z, st, alog + (size_t)l * DI_ * DS_,
                dskip + l * DI_, alpha + l, beta + l, xiny, nstates);
            // h_c += y @ out_proj_w[l]^T
            gemm_bt_kernel<0,0,1><<<dim3(ntok_c/64, DM_/64), blk, 0, stream>>>(
                xiny, DI_, outw_l, nullptr, h_c, DM_, DM_, DI_);
        }
    }

    // out = rmsnorm(h) * rms_g   (in place over d_out)
    rmsnorm_kernel<<<dim3(NTOK), blk, 0, stream>>>(h, rmsg, (float*)d_out);
}

// Round 6
// 3431.400 us; speedup vs baseline: 2.6507x; 1.3614x over previous
//
#include <hip/hip_runtime.h>
#include <hip/hip_bf16.h>
#include <math.h>

#define B_N   32
#define T_N   1024
#define INDIM 60
#define DM_   256
#define L_N   4
#define DS_   32
#define DC_   4
#define DI_   512
#define DTR_  16
#define NTOK  (B_N * T_N)   // 32768
#define TC_   64            // timesteps per scan chunk
#define NC_   16            // chunks (T_N / TC_)

typedef __attribute__((ext_vector_type(8))) short bf16x8;   // 16 B
typedef __attribute__((ext_vector_type(4))) float f32x4;

__device__ __forceinline__ float softplus_f(float x) {
    return x > 20.f ? x : log1pf(__expf(x));
}
__device__ __forceinline__ float silu_f(float x) {
    return x / (1.f + __expf(-x));
}
__device__ __forceinline__ ushort f2bf(float f) {
    __hip_bfloat16 b = __float2bfloat16(f);
    return *reinterpret_cast<ushort*>(&b);
}

// ---------------------------------------------------------------------------
// f32 -> bf16 bulk convert (weights). n multiple of 256.
// ---------------------------------------------------------------------------
__global__ __launch_bounds__(256) void cvt_bf16_kernel(
    const float* __restrict__ in, ushort* __restrict__ out, int n)
{
    const int i = blockIdx.x * 256 + threadIdx.x;
    if (i < n) out[i] = f2bf(in[i]);
}

// ---------------------------------------------------------------------------
// bf16 MFMA GEMM: C[M,N](f32) (+)= A[M,K](bf16) * W[N,K](bf16)^T
// 128x128 tile, BK=64, 256 threads (4 waves, 2x2 of 64x64), 16x16x32 MFMA.
// LDS rows are 128B with slot^(row&7) XOR swizzle.
// Stage copies are 16B (bf16x8) — one full 8-ushort slot per thread.
// M, K multiples of 128/64; N arbitrary (clamped stage rows, masked store).
// ---------------------------------------------------------------------------
template<int ACCUM>
__global__ __launch_bounds__(256) void gemm_mfma_kernel(
    const ushort* __restrict__ A,
    const ushort* __restrict__ W,
    float* __restrict__ C, int ldc,
    int N, int K)
{
    __shared__ __align__(16) ushort As[128 * 64];   // 16 KB
    __shared__ __align__(16) ushort Ws[128 * 64];   // 16 KB
    const int tid  = threadIdx.x;
    const int lane = tid & 63, wid = tid >> 6;
    const int wr = wid >> 1, wc = wid & 1;        // wave -> 64x64 quadrant
    const int m0 = blockIdx.x * 128, n0 = blockIdx.y * 128;
    const int srow  = tid >> 3;      // 0..31 (stage row within 32-row group)
    const int sslot = tid & 7;       // 16B slot within 128B row
    const int l16 = lane & 15, lq = lane >> 4;

    f32x4 acc[4][4] = {};

    for (int k0 = 0; k0 < K; k0 += 64) {
        __syncthreads();   // previous iter's reads done before overwrite
        #pragma unroll
        for (int i = 0; i < 4; ++i) {
            const int row = i * 32 + srow;
            const int dslot = sslot ^ (row & 7);
            {   // A tile: full 16B slot copy
                const ushort* src = A + (size_t)(m0 + row) * K + k0 + sslot * 8;
                *(bf16x8*)&As[row * 64 + dslot * 8] = *(const bf16x8*)src;
            }
            {   // W tile (clamp row for N not multiple of 128)
                int gn = n0 + row; if (gn >= N) gn = N - 1;
                const ushort* src = W + (size_t)gn * K + k0 + sslot * 8;
                *(bf16x8*)&Ws[row * 64 + dslot * 8] = *(const bf16x8*)src;
            }
        }
        __syncthreads();
        #pragma unroll
        for (int ks = 0; ks < 2; ++ks) {
            bf16x8 af[4], bfr[4];
            #pragma unroll
            for (int mi = 0; mi < 4; ++mi) {
                const int row = wr * 64 + mi * 16 + l16;
                const int slot = (ks * 4 + lq) ^ (row & 7);
                af[mi] = *(const bf16x8*)&As[row * 64 + slot * 8];
            }
            #pragma unroll
            for (int ni = 0; ni < 4; ++ni) {
                const int row = wc * 64 + ni * 16 + l16;
                const int slot = (ks * 4 + lq) ^ (row & 7);
                bfr[ni] = *(const bf16x8*)&Ws[row * 64 + slot * 8];
            }
            #pragma unroll
            for (int mi = 0; mi < 4; ++mi)
                #pragma unroll
                for (int ni = 0; ni < 4; ++ni)
                    acc[mi][ni] = __builtin_amdgcn_mfma_f32_16x16x32_bf16(
                        af[mi], bfr[ni], acc[mi][ni], 0, 0, 0);
        }
    }

    // epilogue: C/D layout col = lane&15, row = (lane>>4)*4 + reg  [m89]
    #pragma unroll
    for (int mi = 0; mi < 4; ++mi) {
        #pragma unroll
        for (int ni = 0; ni < 4; ++ni) {
            const int col = n0 + wc * 64 + ni * 16 + l16;
            if (col >= N) continue;
            #pragma unroll
            for (int r = 0; r < 4; ++r) {
                const int rowg = m0 + wr * 64 + mi * 16 + lq * 4 + r;
                float* dst = C + (size_t)rowg * ldc + col;
                float v = acc[mi][ni][r];
                if (ACCUM) v += *dst;
                *dst = v;
            }
        }
    }
}

// ---------------------------------------------------------------------------
// Generic f32 GEMM (kept for fe: K=60, and dt_proj: K=16).
// ---------------------------------------------------------------------------
template<int HAS_BIAS, int ACT_SOFTPLUS, int ACCUM>
__global__ __launch_bounds__(256) void gemm_bt_kernel(
    const float* __restrict__ A, int lda,
    const float* __restrict__ W,
    const float* __restrict__ bias,
    float* __restrict__ C, int ldc,
    int N, int K)
{
    __shared__ float As[16][68];
    __shared__ float Ws[16][68];
    const int tid = threadIdx.x;
    const int tx = tid & 15, ty = tid >> 4;
    const int m0 = blockIdx.x * 64;
    const int n0 = blockIdx.y * 64;
    const int li = tid >> 2;
    const int lj = (tid & 3) << 2;

    float acc[4][4] = {};

    for (int k0 = 0; k0 < K; k0 += 16) {
        const int gk = k0 + lj;
        {
            const float* src = A + (size_t)(m0 + li) * lda + gk;
            float4 v;
            if (gk + 3 < K) {
                v = *(const float4*)src;
            } else {
                v.x = (gk + 0 < K) ? src[0] : 0.f;
                v.y = (gk + 1 < K) ? src[1] : 0.f;
                v.z = (gk + 2 < K) ? src[2] : 0.f;
                v.w = (gk + 3 < K) ? src[3] : 0.f;
            }
            As[lj + 0][li] = v.x; As[lj + 1][li] = v.y;
            As[lj + 2][li] = v.z; As[lj + 3][li] = v.w;
        }
        {
            const int gn = n0 + li;
            float4 v = make_float4(0.f, 0.f, 0.f, 0.f);
            if (gn < N) {
                const float* src = W + (size_t)gn * K + gk;
                if (gk + 3 < K) {
                    v = *(const float4*)src;
                } else {
                    v.x = (gk + 0 < K) ? src[0] : 0.f;
                    v.y = (gk + 1 < K) ? src[1] : 0.f;
                    v.z = (gk + 2 < K) ? src[2] : 0.f;
                    v.w = (gk + 3 < K) ? src[3] : 0.f;
                }
            }
            Ws[lj + 0][li] = v.x; Ws[lj + 1][li] = v.y;
            Ws[lj + 2][li] = v.z; Ws[lj + 3][li] = v.w;
        }
        __syncthreads();
        #pragma unroll
        for (int k = 0; k < 16; ++k) {
            float a0 = As[k][ty * 4 + 0], a1 = As[k][ty * 4 + 1];
            float a2 = As[k][ty * 4 + 2], a3 = As[k][ty * 4 + 3];
            float b0 = Ws[k][tx * 4 + 0], b1 = Ws[k][tx * 4 + 1];
            float b2 = Ws[k][tx * 4 + 2], b3 = Ws[k][tx * 4 + 3];
            acc[0][0] += a0 * b0; acc[0][1] += a0 * b1; acc[0][2] += a0 * b2; acc[0][3] += a0 * b3;
            acc[1][0] += a1 * b0; acc[1][1] += a1 * b1; acc[1][2] += a1 * b2; acc[1][3] += a1 * b3;
            acc[2][0] += a2 * b0; acc[2][1] += a2 * b1; acc[2][2] += a2 * b2; acc[2][3] += a2 * b3;
            acc[3][0] += a3 * b0; acc[3][1] += a3 * b1; acc[3][2] += a3 * b2; acc[3][3] += a3 * b3;
        }
        __syncthreads();
    }

    const int mb = m0 + ty * 4;
    const int nb = n0 + tx * 4;
    #pragma unroll
    for (int r = 0; r < 4; ++r) {
        float* dst = C + (size_t)(mb + r) * ldc + nb;
        if (nb + 3 < N) {
            float4 v = make_float4(acc[r][0], acc[r][1], acc[r][2], acc[r][3]);
            if (HAS_BIAS) {
                float4 bs = *(const float4*)(bias + nb);
                v.x += bs.x; v.y += bs.y; v.z += bs.z; v.w += bs.w;
            }
            if (ACT_SOFTPLUS) {
                v.x = softplus_f(v.x); v.y = softplus_f(v.y);
                v.z = softplus_f(v.z); v.w = softplus_f(v.w);
            }
            if (ACCUM) {
                float4 o = *(const float4*)dst;
                v.x += o.x; v.y += o.y; v.z += o.z; v.w += o.w;
            }
            *(float4*)dst = v;
        } else {
            #pragma unroll
            for (int c = 0; c < 4; ++c) {
                if (nb + c >= N) continue;
                float x = acc[r][c];
                if (HAS_BIAS) x += bias[nb + c];
                if (ACT_SOFTPLUS) x = softplus_f(x);
                if (ACCUM) x += dst[c];
                dst[c] = x;
            }
        }
    }
}

// ---------------------------------------------------------------------------
// LayerNorm(+bias,gamma) + ReLU over DM=256; one token per block.
// ---------------------------------------------------------------------------
__global__ __launch_bounds__(256) void ln_relu_kernel(
    const float* __restrict__ in, const float* __restrict__ g,
    const float* __restrict__ b, float* __restrict__ out)
{
    const int row = blockIdx.x;
    const int d = threadIdx.x;
    const float v = in[(size_t)row * DM_ + d];
    float s = v, s2 = v * v;
    #pragma unroll
    for (int off = 1; off < 64; off <<= 1) {
        s  += __shfl_xor(s, off);
        s2 += __shfl_xor(s2, off);
    }
    __shared__ float sm[8];
    const int wid = threadIdx.x >> 6, lane = threadIdx.x & 63;
    if (lane == 0) { sm[wid] = s; sm[4 + wid] = s2; }
    __syncthreads();
    s  = sm[0] + sm[1] + sm[2] + sm[3];
    s2 = sm[4] + sm[5] + sm[6] + sm[7];
    const float mean = s * (1.f / DM_);
    const float var  = s2 * (1.f / DM_) - mean * mean;
    const float o = (v - mean) * rsqrtf(var + 1e-5f) * g[d] + b[d];
    out[(size_t)row * DM_ + d] = fmaxf(o, 0.f);
}

// ---------------------------------------------------------------------------
// RMSNorm over DM=256; one token per block. BF16OUT: write bf16 (for MFMA A).
// ---------------------------------------------------------------------------
template<int BF16OUT>
__global__ __launch_bounds__(256) void rmsnorm_kernel(
    const float* __restrict__ in, const float* __restrict__ g,
    void* __restrict__ out)
{
    const int row = blockIdx.x;
    const int d = threadIdx.x;
    const float v = in[(size_t)row * DM_ + d];
    float s2 = v * v;
    #pragma unroll
    for (int off = 1; off < 64; off <<= 1) s2 += __shfl_xor(s2, off);
    __shared__ float sm[4];
    const int wid = threadIdx.x >> 6, lane = threadIdx.x & 63;
    if (lane == 0) sm[wid] = s2;
    __syncthreads();
    s2 = sm[0] + sm[1] + sm[2] + sm[3];
    const float o = v * rsqrtf(s2 * (1.f / DM_) + 1e-6f) * g[d];
    if (BF16OUT) ((ushort*)out)[(size_t)row * DM_ + d] = f2bf(o);
    else         ((float*)out)[(size_t)row * DM_ + d] = o;
}

// ---------------------------------------------------------------------------
// Causal depthwise conv (DC=4) + SiLU; writes f32 (scan) and bf16 (GEMM A).
// ---------------------------------------------------------------------------
__global__ __launch_bounds__(256) void conv_silu_kernel(
    const float* __restrict__ xin, const float* __restrict__ cw,
    const float* __restrict__ cb, float* __restrict__ xc,
    ushort* __restrict__ xcb)
{
    const int idx = blockIdx.x * 256 + threadIdx.x;
    const int d  = idx & (DI_ - 1);
    const int bt = idx >> 9;
    const int t  = bt & (T_N - 1);   // chunks start at batch boundaries
    const float4 w = *(const float4*)(cw + d * 4);   // taps k=0..3
    const size_t base = (size_t)bt * DI_ + d;
    float acc = cb[d] + w.w * xin[base];             // k=3 -> t
    if (t >= 1) acc += w.z * xin[base - 1 * DI_];    // k=2 -> t-1
    if (t >= 2) acc += w.y * xin[base - 2 * DI_];    // k=1 -> t-2
    if (t >= 3) acc += w.x * xin[base - 3 * DI_];    // k=0 -> t-3
    const float o = acc * (1.f / (1.f + __expf(-acc)));
    xc[idx]  = o;
    xcb[idx] = f2bf(o);
}

// ---------------------------------------------------------------------------
// Chunk-parallel scan (round-4 derivation, verified). passC emits bf16 y.
// ---------------------------------------------------------------------------
__global__ __launch_bounds__(256) void scan_passA(
    const float* __restrict__ xdbl,
    const float* __restrict__ dlt,
    const float* __restrict__ xc,
    const float* __restrict__ alog,
    const float* __restrict__ alpha_p,
    const float* __restrict__ beta_p,
    float4* __restrict__ agg,
    int nstates)
{
    const int b  = blockIdx.x >> 3;
    const int dg = blockIdx.x & 7;
    const int c  = blockIdx.y;
    const int dl = threadIdx.x >> 2;
    const int sg = threadIdx.x & 3;
    const int d  = dg * 64 + dl;
    const int s0 = sg * 8;
    const float alpha = alpha_p[0];
    const float beta  = beta_p[0];
    const float ab = alpha * beta;

    float A[8];
    #pragma unroll
    for (int j = 0; j < 8; ++j) A[j] = -__expf(alog[d * DS_ + s0 + j]);

    float p11[8], p12[8] = {}, q1[8] = {}, q2[8] = {};
    #pragma unroll
    for (int j = 0; j < 8; ++j) p11[j] = 1.f;
    float pw = 1.f;

    size_t bt = (size_t)b * T_N + (size_t)c * TC_;
    for (int k = 0; k < TC_; ++k, ++bt) {
        const float dv = dlt[bt * DI_ + d];
        const float xt = xc[bt * DI_ + d];
        const float dx = dv * xt;
        const float* row = xdbl + bt * 80;
        const float4 B0 = *(const float4*)(row + 16 + s0);
        const float4 B1 = *(const float4*)(row + 20 + s0);
        const float Bv[8] = {B0.x,B0.y,B0.z,B0.w,B1.x,B1.y,B1.z,B1.w};
        pw *= beta;
        const float apw = alpha * pw;
        #pragma unroll
        for (int j = 0; j < 8; ++j) {
            const float dA  = __expf(dv * A[j]);
            const float dBx = dx * Bv[j];
            q1[j]  = dA * q1[j] + ab * q2[j] + dBx;
            q2[j]  = beta * q2[j] + dBx;
            p12[j] = dA * p12[j] + apw;
            p11[j] *= dA;
        }
    }
    const size_t sidb = ((size_t)b * DI_ + d) * DS_ + s0;
    #pragma unroll
    for (int j = 0; j < 8; ++j)
        agg[(size_t)c * nstates + sidb + j] =
            make_float4(p11[j], p12[j], q1[j], q2[j]);
}

__global__ __launch_bounds__(256) void scan_passB(
    const float4* __restrict__ agg, float2* __restrict__ st,
    const float* __restrict__ beta_p, int nstates)
{
    const int sid = blockIdx.x * 256 + threadIdx.x;
    if (sid >= nstates) return;
    float bTc = beta_p[0];
    #pragma unroll
    for (int i = 0; i < 6; ++i) bTc *= bTc;   // beta^64
    float h = 0.f, v = 0.f;
    for (int c = 0; c < NC_; ++c) {
        st[(size_t)c * nstates + sid] = make_float2(h, v);
        const float4 a = agg[(size_t)c * nstates + sid];
        const float hn = a.x * h + a.y * v + a.z;
        v = bTc * v + a.w;
        h = hn;
    }
}

__global__ __launch_bounds__(256) void scan_passC(
    const float* __restrict__ xdbl,
    const float* __restrict__ dlt,
    const float* __restrict__ xc,
    const float* __restrict__ z,
    const float2* __restrict__ st,
    const float* __restrict__ alog,
    const float* __restrict__ dskip,
    const float* __restrict__ alpha_p,
    const float* __restrict__ beta_p,
    ushort* __restrict__ y,            // bf16 out for out_proj MFMA
    int nstates)
{
    const int b  = blockIdx.x >> 3;
    const int dg = blockIdx.x & 7;
    const int c  = blockIdx.y;
    const int dl = threadIdx.x >> 2;
    const int sg = threadIdx.x & 3;
    const int d  = dg * 64 + dl;
    const int s0 = sg * 8;
    const float alpha = alpha_p[0];
    const float beta  = beta_p[0];
    const float na  = 1.f - alpha;
    const float dsk = dskip[d];

    float A[8];
    #pragma unroll
    for (int j = 0; j < 8; ++j) A[j] = -__expf(alog[d * DS_ + s0 + j]);

    const size_t sidb = ((size_t)b * DI_ + d) * DS_ + s0;
    float hs[8], vs[8];
    #pragma unroll
    for (int j = 0; j < 8; ++j) {
        const float2 s_ = st[(size_t)c * nstates + sidb + j];
        hs[j] = s_.x; vs[j] = s_.y;
    }

    size_t bt = (size_t)b * T_N + (size_t)c * TC_;
    for (int k = 0; k < TC_; ++k, ++bt) {
        const float dv = dlt[bt * DI_ + d];
        const float xt = xc[bt * DI_ + d];
        const float dx = dv * xt;
        const float* row = xdbl + bt * 80;
        const float4 B0 = *(const float4*)(row + 16 + s0);
        const float4 B1 = *(const float4*)(row + 20 + s0);
        const float4 C0 = *(const float4*)(row + 48 + s0);
        const float4 C1 = *(const float4*)(row + 52 + s0);
        const float Bv[8] = {B0.x,B0.y,B0.z,B0.w,B1.x,B1.y,B1.z,B1.w};
        const float Cv[8] = {C0.x,C0.y,C0.z,C0.w,C1.x,C1.y,C1.z,C1.w};
        float ysum = 0.f;
        #pragma unroll
        for (int j = 0; j < 8; ++j) {
            const float dA  = __expf(dv * A[j]);
            const float dBx = dx * Bv[j];
            vs[j] = beta * vs[j] + dBx;
            hs[j] = dA * hs[j] + (alpha * vs[j] + na * dBx);
            ysum += hs[j] * Cv[j];
        }
        ysum += __shfl_xor(ysum, 1);
        ysum += __shfl_xor(ysum, 2);
        if (sg == 0) {
            const float zv = z[bt * DI_ + d];
            y[bt * DI_ + d] = f2bf((ysum + dsk * xt) * silu_f(zv));
        }
    }
}

// ---------------------------------------------------------------------------
extern "C" void kernel_launch(void* const* d_in, const int* in_sizes, int n_in,
                              void* d_out, int out_size, void* d_ws, size_t ws_size,
                              hipStream_t stream)
{
    const float* x     = (const float*)d_in[0];
    const float* fe_w  = (const float*)d_in[1];
    const float* fe_b  = (const float*)d_in[2];
    const float* ln_g  = (const float*)d_in[3];
    const float* ln_b  = (const float*)d_in[4];
    const float* bng   = (const float*)d_in[5];
    const float* inw   = (const float*)d_in[6];
    const float* convw = (const float*)d_in[7];
    const float* convb = (const float*)d_in[8];
    const float* xpw   = (const float*)d_in[9];
    const float* dtw   = (const float*)d_in[10];
    const float* dtb   = (const float*)d_in[11];
    const float* alog  = (const float*)d_in[12];
    const float* dskip = (const float*)d_in[13];
    const float* outw  = (const float*)d_in[14];
    const float* alpha = (const float*)d_in[15];
    const float* beta  = (const float*)d_in[16];
    const float* rmsg  = (const float*)d_in[17];

    // -------- workspace (floats). Per-nb true need = 4,063,232 fl. --------
    // nb=16 -> 16*4,063,232 + 868,352 = 65,880,064 fl = 263.5 MB.
    const size_t avail = ws_size / 4;
    int nb = 16;
    while (nb > 4 && (size_t)nb * 4063232ULL + 868352ULL > avail) nb >>= 1;
    const int ntok_c  = nb * 1024;
    const int nstates = nb * DI_ * DS_;

    float*  ws   = (float*)d_ws;
    ushort* u_b  = (ushort*)ws;                       // ntok*256 bf16 (dead b4 xdbl)
    float*  xdbl = ws;                                // ntok*80 f32 (overlays u_b)
    float*  x_in = ws + (size_t)ntok_c * 128;         // ntok*512
    float*  z    = x_in + (size_t)ntok_c * 512;       // ntok*512
    float*  xc   = z    + (size_t)ntok_c * 512;       // ntok*512
    ushort* xcb  = (ushort*)(xc + (size_t)ntok_c * 512); // ntok*512 bf16 (-> y_b)
    float*  dlt  = xc + (size_t)ntok_c * 512 + (size_t)ntok_c * 256; // ntok*512
    float4* agg  = (float4*)(dlt + (size_t)ntok_c * 512);            // nstates*NC
    float2* st   = (float2*)((float*)agg + (size_t)nstates * NC_ * 4);
    ushort* wbuf = (ushort*)((float*)st + (size_t)nstates * NC_ * 2);

    ushort* inw_b  = wbuf;                       // L*1024*256
    ushort* xpw_b  = inw_b + 4 * 1024 * 256;     // L*80*512
    ushort* outw_b = xpw_b + 4 * 80 * 512;       // L*256*512
    ushort* y_b    = xcb;                        // reuse (xcb dead after x_proj)

    float* h   = (float*)d_out;   // persistent hidden state (B,T,DM)
    float* pre = ws;              // fe temp overlay (consumed immediately)

    const dim3 blk(256);

    // weights -> bf16 (once per launch)
    cvt_bf16_kernel<<<dim3(L_N * 1024 * 256 / 256), blk, 0, stream>>>(inw, inw_b, L_N * 1024 * 256);
    cvt_bf16_kernel<<<dim3(L_N * 80 * 512 / 256), blk, 0, stream>>>(xpw, xpw_b, L_N * 80 * 512);
    cvt_bf16_kernel<<<dim3(L_N * 256 * 512 / 256), blk, 0, stream>>>(outw, outw_b, L_N * 256 * 512);

    // feature extract: pre = x @ fe_w^T + fe_b ; h = relu(LN(pre))
    gemm_bt_kernel<1,0,0><<<dim3(NTOK/64, DM_/64), blk, 0, stream>>>(
        x, INDIM, fe_w, fe_b, pre, DM_, DM_, INDIM);
    ln_relu_kernel<<<dim3(NTOK), blk, 0, stream>>>(pre, ln_g, ln_b, h);

    for (int l = 0; l < L_N; ++l) {
        const ushort* inw_l  = inw_b  + (size_t)l * 2 * DI_ * DM_;
        const ushort* xpw_l  = xpw_b  + (size_t)l * 80 * DI_;
        const float*  dtw_l  = dtw    + (size_t)l * DI_ * DTR_;
        const ushort* outw_l = outw_b + (size_t)l * DM_ * DI_;

        for (int b0 = 0; b0 < B_N; b0 += nb) {
            float* h_c = h + (size_t)b0 * 1024 * DM_;
            // u_b = bf16(rmsnorm(h_c) * blk_norm_g[l])
            rmsnorm_kernel<1><<<dim3(ntok_c), blk, 0, stream>>>(h_c, bng + l * DM_, u_b);
            // x_in = u @ inw[0:DI]^T ; z = u @ inw[DI:2DI]^T   (bf16 MFMA)
            gemm_mfma_kernel<0><<<dim3(ntok_c/128, DI_/128), blk, 0, stream>>>(
                u_b, inw_l, x_in, DI_, DI_, DM_);
            gemm_mfma_kernel<0><<<dim3(ntok_c/128, DI_/128), blk, 0, stream>>>(
                u_b, inw_l + (size_t)DI_ * DM_, z, DI_, DI_, DM_);
            // xc (f32) + xcb (bf16) = silu(causal_conv(x_in) + cb)
            conv_silu_kernel<<<dim3((ntok_c * DI_) / 256), blk, 0, stream>>>(
                x_in, convw + l * DI_ * DC_, convb + l * DI_, xc, xcb);
            // x_dbl = xcb @ xpw^T  (bf16 MFMA, N=80 masked; overlays u_b)
            gemm_mfma_kernel<0><<<dim3(ntok_c/128, 1), blk, 0, stream>>>(
                xcb, xpw_l, xdbl, 80, 80, DI_);
            // delta = softplus(x_dbl[:, :16] @ dtw^T + dtb)  (f32, K=16)
            gemm_bt_kernel<1,1,0><<<dim3(ntok_c/64, DI_/64), blk, 0, stream>>>(
                xdbl, 80, dtw_l, dtb + l * DI_, dlt, DI_, DI_, DTR_);
            // chunk-parallel scan
            scan_passA<<<dim3(nb * 8, NC_), blk, 0, stream>>>(
                xdbl, dlt, xc, alog + (size_t)l * DI_ * DS_, alpha + l, beta + l,
                agg, nstates);
            scan_passB<<<dim3((nstates + 255) / 256), blk, 0, stream>>>(
                agg, st, beta + l, nstates);
            scan_passC<<<dim3(nb * 8, NC_), blk, 0, stream>>>(
                xdbl, dlt, xc, z, st, alog + (size_t)l * DI_ * DS_,
                dskip + l * DI_, alpha + l, beta + l, y_b, nstates);
            // h_c += y @ outw^T  (bf16 MFMA, accumulate)
            gemm_mfma_kernel<1><<<dim3(ntok_c/128, DM_/128), blk, 0, stream>>>(
                y_b, outw_l, h_c, DM_, DM_, DI_);
        }
    }

    // out = rmsnorm(h) * rms_g   (in place over d_out)
    rmsnorm_kernel<0><<<dim3(NTOK), blk, 0, stream>>>(h, rmsg, (float*)d_out);
}

// Round 7
// 2898.692 us; speedup vs baseline: 3.1379x; 1.1838x over previous
//
#include <hip/hip_runtime.h>
#include <hip/hip_bf16.h>
#include <math.h>

#define B_N   32
#define T_N   1024
#define INDIM 60
#define DM_   256
#define L_N   4
#define DS_   32
#define DC_   4
#define DI_   512
#define DTR_  16
#define NTOK  (B_N * T_N)   // 32768
#define TC_   64            // timesteps per scan chunk
#define NC_   16            // chunks (T_N / TC_)

typedef __attribute__((ext_vector_type(8))) short bf16x8;   // 16 B
typedef __attribute__((ext_vector_type(4))) float f32x4;
typedef __attribute__((ext_vector_type(2))) float f32x2;

#define LOG2E 1.4426950408889634f

__device__ __forceinline__ float softplus_f(float x) {
    return x > 20.f ? x : log1pf(__expf(x));
}
__device__ __forceinline__ float silu_f(float x) {
    return x / (1.f + __expf(-x));
}
__device__ __forceinline__ ushort f2bf(float f) {
    __hip_bfloat16 b = __float2bfloat16(f);
    return *reinterpret_cast<ushort*>(&b);
}
__device__ __forceinline__ float exp2_fast(float x) {
#if __has_builtin(__builtin_amdgcn_exp2f)
    return __builtin_amdgcn_exp2f(x);
#else
    return __expf(x * 0.6931471805599453f);
#endif
}

// ---------------------------------------------------------------------------
// f32 -> bf16 bulk convert (weights). n multiple of 256.
// ---------------------------------------------------------------------------
__global__ __launch_bounds__(256) void cvt_bf16_kernel(
    const float* __restrict__ in, ushort* __restrict__ out, int n)
{
    const int i = blockIdx.x * 256 + threadIdx.x;
    if (i < n) out[i] = f2bf(in[i]);
}

// ---------------------------------------------------------------------------
// bf16 MFMA GEMM: C[M,N](f32) (+)= A[M,K](bf16) * W[N,K](bf16)^T
// 128x128 tile, BK=64, 256 threads (4 waves), 16x16x32 MFMA, XOR-swizzled LDS.
// ---------------------------------------------------------------------------
template<int ACCUM>
__global__ __launch_bounds__(256) void gemm_mfma_kernel(
    const ushort* __restrict__ A,
    const ushort* __restrict__ W,
    float* __restrict__ C, int ldc,
    int N, int K)
{
    __shared__ __align__(16) ushort As[128 * 64];   // 16 KB
    __shared__ __align__(16) ushort Ws[128 * 64];   // 16 KB
    const int tid  = threadIdx.x;
    const int lane = tid & 63, wid = tid >> 6;
    const int wr = wid >> 1, wc = wid & 1;        // wave -> 64x64 quadrant
    const int m0 = blockIdx.x * 128, n0 = blockIdx.y * 128;
    const int srow  = tid >> 3;      // 0..31 (stage row within 32-row group)
    const int sslot = tid & 7;       // 16B slot within 128B row
    const int l16 = lane & 15, lq = lane >> 4;

    f32x4 acc[4][4] = {};

    for (int k0 = 0; k0 < K; k0 += 64) {
        __syncthreads();
        #pragma unroll
        for (int i = 0; i < 4; ++i) {
            const int row = i * 32 + srow;
            const int dslot = sslot ^ (row & 7);
            {   // A tile: full 16B slot copy
                const ushort* src = A + (size_t)(m0 + row) * K + k0 + sslot * 8;
                *(bf16x8*)&As[row * 64 + dslot * 8] = *(const bf16x8*)src;
            }
            {   // W tile (clamp row for N not multiple of 128)
                int gn = n0 + row; if (gn >= N) gn = N - 1;
                const ushort* src = W + (size_t)gn * K + k0 + sslot * 8;
                *(bf16x8*)&Ws[row * 64 + dslot * 8] = *(const bf16x8*)src;
            }
        }
        __syncthreads();
        #pragma unroll
        for (int ks = 0; ks < 2; ++ks) {
            bf16x8 af[4], bfr[4];
            #pragma unroll
            for (int mi = 0; mi < 4; ++mi) {
                const int row = wr * 64 + mi * 16 + l16;
                const int slot = (ks * 4 + lq) ^ (row & 7);
                af[mi] = *(const bf16x8*)&As[row * 64 + slot * 8];
            }
            #pragma unroll
            for (int ni = 0; ni < 4; ++ni) {
                const int row = wc * 64 + ni * 16 + l16;
                const int slot = (ks * 4 + lq) ^ (row & 7);
                bfr[ni] = *(const bf16x8*)&Ws[row * 64 + slot * 8];
            }
            #pragma unroll
            for (int mi = 0; mi < 4; ++mi)
                #pragma unroll
                for (int ni = 0; ni < 4; ++ni)
                    acc[mi][ni] = __builtin_amdgcn_mfma_f32_16x16x32_bf16(
                        af[mi], bfr[ni], acc[mi][ni], 0, 0, 0);
        }
    }

    // epilogue: C/D layout col = lane&15, row = (lane>>4)*4 + reg  [m89]
    #pragma unroll
    for (int mi = 0; mi < 4; ++mi) {
        #pragma unroll
        for (int ni = 0; ni < 4; ++ni) {
            const int col = n0 + wc * 64 + ni * 16 + l16;
            if (col >= N) continue;
            #pragma unroll
            for (int r = 0; r < 4; ++r) {
                const int rowg = m0 + wr * 64 + mi * 16 + lq * 4 + r;
                float* dst = C + (size_t)rowg * ldc + col;
                float v = acc[mi][ni][r];
                if (ACCUM) v += *dst;
                *dst = v;
            }
        }
    }
}

// ---------------------------------------------------------------------------
// Generic f32 GEMM (kept for fe: K=60, and dt_proj: K=16).
// ---------------------------------------------------------------------------
template<int HAS_BIAS, int ACT_SOFTPLUS, int ACCUM>
__global__ __launch_bounds__(256) void gemm_bt_kernel(
    const float* __restrict__ A, int lda,
    const float* __restrict__ W,
    const float* __restrict__ bias,
    float* __restrict__ C, int ldc,
    int N, int K)
{
    __shared__ float As[16][68];
    __shared__ float Ws[16][68];
    const int tid = threadIdx.x;
    const int tx = tid & 15, ty = tid >> 4;
    const int m0 = blockIdx.x * 64;
    const int n0 = blockIdx.y * 64;
    const int li = tid >> 2;
    const int lj = (tid & 3) << 2;

    float acc[4][4] = {};

    for (int k0 = 0; k0 < K; k0 += 16) {
        const int gk = k0 + lj;
        {
            const float* src = A + (size_t)(m0 + li) * lda + gk;
            float4 v;
            if (gk + 3 < K) {
                v = *(const float4*)src;
            } else {
                v.x = (gk + 0 < K) ? src[0] : 0.f;
                v.y = (gk + 1 < K) ? src[1] : 0.f;
                v.z = (gk + 2 < K) ? src[2] : 0.f;
                v.w = (gk + 3 < K) ? src[3] : 0.f;
            }
            As[lj + 0][li] = v.x; As[lj + 1][li] = v.y;
            As[lj + 2][li] = v.z; As[lj + 3][li] = v.w;
        }
        {
            const int gn = n0 + li;
            float4 v = make_float4(0.f, 0.f, 0.f, 0.f);
            if (gn < N) {
                const float* src = W + (size_t)gn * K + gk;
                if (gk + 3 < K) {
                    v = *(const float4*)src;
                } else {
                    v.x = (gk + 0 < K) ? src[0] : 0.f;
                    v.y = (gk + 1 < K) ? src[1] : 0.f;
                    v.z = (gk + 2 < K) ? src[2] : 0.f;
                    v.w = (gk + 3 < K) ? src[3] : 0.f;
                }
            }
            Ws[lj + 0][li] = v.x; Ws[lj + 1][li] = v.y;
            Ws[lj + 2][li] = v.z; Ws[lj + 3][li] = v.w;
        }
        __syncthreads();
        #pragma unroll
        for (int k = 0; k < 16; ++k) {
            float a0 = As[k][ty * 4 + 0], a1 = As[k][ty * 4 + 1];
            float a2 = As[k][ty * 4 + 2], a3 = As[k][ty * 4 + 3];
            float b0 = Ws[k][tx * 4 + 0], b1 = Ws[k][tx * 4 + 1];
            float b2 = Ws[k][tx * 4 + 2], b3 = Ws[k][tx * 4 + 3];
            acc[0][0] += a0 * b0; acc[0][1] += a0 * b1; acc[0][2] += a0 * b2; acc[0][3] += a0 * b3;
            acc[1][0] += a1 * b0; acc[1][1] += a1 * b1; acc[1][2] += a1 * b2; acc[1][3] += a1 * b3;
            acc[2][0] += a2 * b0; acc[2][1] += a2 * b1; acc[2][2] += a2 * b2; acc[2][3] += a2 * b3;
            acc[3][0] += a3 * b0; acc[3][1] += a3 * b1; acc[3][2] += a3 * b2; acc[3][3] += a3 * b3;
        }
        __syncthreads();
    }

    const int mb = m0 + ty * 4;
    const int nb = n0 + tx * 4;
    #pragma unroll
    for (int r = 0; r < 4; ++r) {
        float* dst = C + (size_t)(mb + r) * ldc + nb;
        if (nb + 3 < N) {
            float4 v = make_float4(acc[r][0], acc[r][1], acc[r][2], acc[r][3]);
            if (HAS_BIAS) {
                float4 bs = *(const float4*)(bias + nb);
                v.x += bs.x; v.y += bs.y; v.z += bs.z; v.w += bs.w;
            }
            if (ACT_SOFTPLUS) {
                v.x = softplus_f(v.x); v.y = softplus_f(v.y);
                v.z = softplus_f(v.z); v.w = softplus_f(v.w);
            }
            if (ACCUM) {
                float4 o = *(const float4*)dst;
                v.x += o.x; v.y += o.y; v.z += o.z; v.w += o.w;
            }
            *(float4*)dst = v;
        } else {
            #pragma unroll
            for (int c = 0; c < 4; ++c) {
                if (nb + c >= N) continue;
                float x = acc[r][c];
                if (HAS_BIAS) x += bias[nb + c];
                if (ACT_SOFTPLUS) x = softplus_f(x);
                if (ACCUM) x += dst[c];
                dst[c] = x;
            }
        }
    }
}

// ---------------------------------------------------------------------------
// LayerNorm(+bias,gamma) + ReLU over DM=256; one token per block.
// ---------------------------------------------------------------------------
__global__ __launch_bounds__(256) void ln_relu_kernel(
    const float* __restrict__ in, const float* __restrict__ g,
    const float* __restrict__ b, float* __restrict__ out)
{
    const int row = blockIdx.x;
    const int d = threadIdx.x;
    const float v = in[(size_t)row * DM_ + d];
    float s = v, s2 = v * v;
    #pragma unroll
    for (int off = 1; off < 64; off <<= 1) {
        s  += __shfl_xor(s, off);
        s2 += __shfl_xor(s2, off);
    }
    __shared__ float sm[8];
    const int wid = threadIdx.x >> 6, lane = threadIdx.x & 63;
    if (lane == 0) { sm[wid] = s; sm[4 + wid] = s2; }
    __syncthreads();
    s  = sm[0] + sm[1] + sm[2] + sm[3];
    s2 = sm[4] + sm[5] + sm[6] + sm[7];
    const float mean = s * (1.f / DM_);
    const float var  = s2 * (1.f / DM_) - mean * mean;
    const float o = (v - mean) * rsqrtf(var + 1e-5f) * g[d] + b[d];
    out[(size_t)row * DM_ + d] = fmaxf(o, 0.f);
}

// ---------------------------------------------------------------------------
// RMSNorm over DM=256; one token per block. BF16OUT: write bf16 (for MFMA A).
// ---------------------------------------------------------------------------
template<int BF16OUT>
__global__ __launch_bounds__(256) void rmsnorm_kernel(
    const float* __restrict__ in, const float* __restrict__ g,
    void* __restrict__ out)
{
    const int row = blockIdx.x;
    const int d = threadIdx.x;
    const float v = in[(size_t)row * DM_ + d];
    float s2 = v * v;
    #pragma unroll
    for (int off = 1; off < 64; off <<= 1) s2 += __shfl_xor(s2, off);
    __shared__ float sm[4];
    const int wid = threadIdx.x >> 6, lane = threadIdx.x & 63;
    if (lane == 0) sm[wid] = s2;
    __syncthreads();
    s2 = sm[0] + sm[1] + sm[2] + sm[3];
    const float o = v * rsqrtf(s2 * (1.f / DM_) + 1e-6f) * g[d];
    if (BF16OUT) ((ushort*)out)[(size_t)row * DM_ + d] = f2bf(o);
    else         ((float*)out)[(size_t)row * DM_ + d] = o;
}

// ---------------------------------------------------------------------------
// Causal depthwise conv (DC=4) + SiLU over xz[...,:DI] (row stride 1024).
// Writes xc (f32, stride DI) and xcb (bf16, stride DI).
// ---------------------------------------------------------------------------
__global__ __launch_bounds__(256) void conv_silu_kernel(
    const float* __restrict__ xz, const float* __restrict__ cw,
    const float* __restrict__ cb, float* __restrict__ xc,
    ushort* __restrict__ xcb)
{
    const int idx = blockIdx.x * 256 + threadIdx.x;
    const int d  = idx & (DI_ - 1);
    const int bt = idx >> 9;
    const int t  = bt & (T_N - 1);   // chunks start at batch boundaries
    const float4 w = *(const float4*)(cw + d * 4);   // taps k=0..3
    const size_t base = (size_t)bt * 1024 + d;
    float acc = cb[d] + w.w * xz[base];              // k=3 -> t
    if (t >= 1) acc += w.z * xz[base - 1 * 1024];    // k=2 -> t-1
    if (t >= 2) acc += w.y * xz[base - 2 * 1024];    // k=1 -> t-2
    if (t >= 3) acc += w.x * xz[base - 3 * 1024];    // k=0 -> t-3
    const float o = acc * (1.f / (1.f + __expf(-acc)));
    xc[idx]  = o;
    xcb[idx] = f2bf(o);
}

// ---------------------------------------------------------------------------
// Chunk-parallel scan, f32x2-packed states (targets v_pk_fma_f32/v_pk_mul_f32)
// and exp2 with log2e folded into A. Layout/algebra identical to round 4.
// ---------------------------------------------------------------------------
__global__ __launch_bounds__(256) void scan_passA(
    const float* __restrict__ xdbl,
    const float* __restrict__ dlt,
    const float* __restrict__ xc,
    const float* __restrict__ alog,
    const float* __restrict__ alpha_p,
    const float* __restrict__ beta_p,
    float4* __restrict__ agg,
    int nstates)
{
    const int b  = blockIdx.x >> 3;
    const int dg = blockIdx.x & 7;
    const int c  = blockIdx.y;
    const int dl = threadIdx.x >> 2;
    const int sg = threadIdx.x & 3;
    const int d  = dg * 64 + dl;
    const int s0 = sg * 8;
    const float alpha = alpha_p[0];
    const float beta  = beta_p[0];
    const float ab = alpha * beta;

    f32x2 A2[4];
    #pragma unroll
    for (int j = 0; j < 4; ++j) {
        A2[j].x = -__expf(alog[d * DS_ + s0 + 2*j])     * LOG2E;
        A2[j].y = -__expf(alog[d * DS_ + s0 + 2*j + 1]) * LOG2E;
    }

    f32x2 p11[4], p12[4] = {}, q1[4] = {}, q2[4] = {};
    #pragma unroll
    for (int j = 0; j < 4; ++j) { p11[j].x = 1.f; p11[j].y = 1.f; }
    float pw = 1.f;

    size_t bt = (size_t)b * T_N + (size_t)c * TC_;
    for (int k = 0; k < TC_; ++k, ++bt) {
        const float dv = dlt[bt * DI_ + d];
        const float xt = xc[bt * DI_ + d];
        const float dx = dv * xt;
        const float* row = xdbl + bt * 80;
        const float4 B0 = *(const float4*)(row + 16 + s0);
        const float4 B1 = *(const float4*)(row + 20 + s0);
        const f32x2 Bv[4] = {{B0.x,B0.y},{B0.z,B0.w},{B1.x,B1.y},{B1.z,B1.w}};
        pw *= beta;
        const float apw = alpha * pw;
        const f32x2 dv2  = {dv, dv};
        const f32x2 dx2  = {dx, dx};
        const f32x2 ab2  = {ab, ab};
        const f32x2 bet2 = {beta, beta};
        const f32x2 apw2 = {apw, apw};
        #pragma unroll
        for (int j = 0; j < 4; ++j) {
            const f32x2 tE = dv2 * A2[j];                       // pk_mul
            f32x2 dA; dA.x = exp2_fast(tE.x); dA.y = exp2_fast(tE.y);
            const f32x2 dBx = dx2 * Bv[j];                      // pk_mul
            q1[j]  = dA * q1[j] + (ab2 * q2[j] + dBx);          // 2x pk_fma
            q2[j]  = bet2 * q2[j] + dBx;                        // pk_fma
            p12[j] = dA * p12[j] + apw2;                        // pk_fma
            p11[j] = p11[j] * dA;                               // pk_mul
        }
    }
    const size_t sidb = ((size_t)b * DI_ + d) * DS_ + s0;
    #pragma unroll
    for (int j = 0; j < 4; ++j) {
        agg[(size_t)c * nstates + sidb + 2*j] =
            make_float4(p11[j].x, p12[j].x, q1[j].x, q2[j].x);
        agg[(size_t)c * nstates + sidb + 2*j + 1] =
            make_float4(p11[j].y, p12[j].y, q1[j].y, q2[j].y);
    }
}

__global__ __launch_bounds__(256) void scan_passB(
    const float4* __restrict__ agg, float2* __restrict__ st,
    const float* __restrict__ beta_p, int nstates)
{
    const int sid = blockIdx.x * 256 + threadIdx.x;
    if (sid >= nstates) return;
    float bTc = beta_p[0];
    #pragma unroll
    for (int i = 0; i < 6; ++i) bTc *= bTc;   // beta^64
    float h = 0.f, v = 0.f;
    for (int c = 0; c < NC_; ++c) {
        st[(size_t)c * nstates + sid] = make_float2(h, v);
        const float4 a = agg[(size_t)c * nstates + sid];
        const float hn = a.x * h + a.y * v + a.z;
        v = bTc * v + a.w;
        h = hn;
    }
}

__global__ __launch_bounds__(256) void scan_passC(
    const float* __restrict__ xdbl,
    const float* __restrict__ dlt,
    const float* __restrict__ xc,
    const float* __restrict__ z,       // xz + DI_, row stride 1024
    const float2* __restrict__ st,
    const float* __restrict__ alog,
    const float* __restrict__ dskip,
    const float* __restrict__ alpha_p,
    const float* __restrict__ beta_p,
    ushort* __restrict__ y,            // bf16 out for out_proj MFMA
    int nstates)
{
    const int b  = blockIdx.x >> 3;
    const int dg = blockIdx.x & 7;
    const int c  = blockIdx.y;
    const int dl = threadIdx.x >> 2;
    const int sg = threadIdx.x & 3;
    const int d  = dg * 64 + dl;
    const int s0 = sg * 8;
    const float alpha = alpha_p[0];
    const float beta  = beta_p[0];
    const float na  = 1.f - alpha;
    const float dsk = dskip[d];

    f32x2 A2[4];
    #pragma unroll
    for (int j = 0; j < 4; ++j) {
        A2[j].x = -__expf(alog[d * DS_ + s0 + 2*j])     * LOG2E;
        A2[j].y = -__expf(alog[d * DS_ + s0 + 2*j + 1]) * LOG2E;
    }

    const size_t sidb = ((size_t)b * DI_ + d) * DS_ + s0;
    f32x2 hs[4], vs[4];
    #pragma unroll
    for (int j = 0; j < 4; ++j) {
        const float2 sa = st[(size_t)c * nstates + sidb + 2*j];
        const float2 sb = st[(size_t)c * nstates + sidb + 2*j + 1];
        hs[j].x = sa.x; hs[j].y = sb.x;
        vs[j].x = sa.y; vs[j].y = sb.y;
    }

    const f32x2 al2 = {alpha, alpha};
    const f32x2 na2 = {na, na};
    const f32x2 bet2 = {beta, beta};

    size_t bt = (size_t)b * T_N + (size_t)c * TC_;
    for (int k = 0; k < TC_; ++k, ++bt) {
        const float dv = dlt[bt * DI_ + d];
        const float xt = xc[bt * DI_ + d];
        const float dx = dv * xt;
        const float* row = xdbl + bt * 80;
        const float4 B0 = *(const float4*)(row + 16 + s0);
        const float4 B1 = *(const float4*)(row + 20 + s0);
        const float4 C0 = *(const float4*)(row + 48 + s0);
        const float4 C1 = *(const float4*)(row + 52 + s0);
        const f32x2 Bv[4] = {{B0.x,B0.y},{B0.z,B0.w},{B1.x,B1.y},{B1.z,B1.w}};
        const f32x2 Cv[4] = {{C0.x,C0.y},{C0.z,C0.w},{C1.x,C1.y},{C1.z,C1.w}};
        const f32x2 dv2 = {dv, dv};
        const f32x2 dx2 = {dx, dx};
        f32x2 ys2 = {0.f, 0.f};
        #pragma unroll
        for (int j = 0; j < 4; ++j) {
            const f32x2 tE = dv2 * A2[j];                       // pk_mul
            f32x2 dA; dA.x = exp2_fast(tE.x); dA.y = exp2_fast(tE.y);
            const f32x2 dBx = dx2 * Bv[j];                      // pk_mul
            vs[j] = bet2 * vs[j] + dBx;                         // pk_fma
            hs[j] = dA * hs[j] + (al2 * vs[j] + na2 * dBx);     // pk_mul+2fma
            ys2   = ys2 + hs[j] * Cv[j];                        // pk_fma
        }
        float ysum = ys2.x + ys2.y;
        ysum += __shfl_xor(ysum, 1);
        ysum += __shfl_xor(ysum, 2);
        if (sg == 0) {
            const float zv = z[bt * 1024 + d];
            y[bt * DI_ + d] = f2bf((ysum + dsk * xt) * silu_f(zv));
        }
    }
}

// ---------------------------------------------------------------------------
extern "C" void kernel_launch(void* const* d_in, const int* in_sizes, int n_in,
                              void* d_out, int out_size, void* d_ws, size_t ws_size,
                              hipStream_t stream)
{
    const float* x     = (const float*)d_in[0];
    const float* fe_w  = (const float*)d_in[1];
    const float* fe_b  = (const float*)d_in[2];
    const float* ln_g  = (const float*)d_in[3];
    const float* ln_b  = (const float*)d_in[4];
    const float* bng   = (const float*)d_in[5];
    const float* inw   = (const float*)d_in[6];
    const float* convw = (const float*)d_in[7];
    const float* convb = (const float*)d_in[8];
    const float* xpw   = (const float*)d_in[9];
    const float* dtw   = (const float*)d_in[10];
    const float* dtb   = (const float*)d_in[11];
    const float* alog  = (const float*)d_in[12];
    const float* dskip = (const float*)d_in[13];
    const float* outw  = (const float*)d_in[14];
    const float* alpha = (const float*)d_in[15];
    const float* beta  = (const float*)d_in[16];
    const float* rmsg  = (const float*)d_in[17];

    // -------- workspace (floats). Per-nb need = 4,063,232 fl (as r6). ----
    const size_t avail = ws_size / 4;
    int nb = 16;
    while (nb > 4 && (size_t)nb * 4063232ULL + 868352ULL > avail) nb >>= 1;
    const int ntok_c  = nb * 1024;
    const int nstates = nb * DI_ * DS_;

    float*  ws   = (float*)d_ws;
    ushort* u_b  = (ushort*)ws;                       // ntok*256 bf16 (dead b4 xdbl)
    float*  xdbl = ws;                                // ntok*80 f32 (overlays u_b)
    float*  xz   = ws + (size_t)ntok_c * 128;         // ntok*1024 (x_in | z)
    float*  xc   = xz + (size_t)ntok_c * 1024;        // ntok*512
    ushort* xcb  = (ushort*)(xc + (size_t)ntok_c * 512); // ntok*512 bf16 (-> y_b)
    float*  dlt  = xc + (size_t)ntok_c * 512 + (size_t)ntok_c * 256; // ntok*512
    float4* agg  = (float4*)(dlt + (size_t)ntok_c * 512);            // nstates*NC
    float2* st   = (float2*)((float*)agg + (size_t)nstates * NC_ * 4);
    ushort* wbuf = (ushort*)((float*)st + (size_t)nstates * NC_ * 2);

    ushort* inw_b  = wbuf;                       // L*1024*256
    ushort* xpw_b  = inw_b + 4 * 1024 * 256;     // L*80*512
    ushort* outw_b = xpw_b + 4 * 80 * 512;       // L*256*512
    ushort* y_b    = xcb;                        // reuse (xcb dead after x_proj)

    float* h   = (float*)d_out;   // persistent hidden state (B,T,DM)
    float* pre = ws;              // fe temp overlay (consumed immediately)

    const dim3 blk(256);

    // weights -> bf16 (once per launch)
    cvt_bf16_kernel<<<dim3(L_N * 1024 * 256 / 256), blk, 0, stream>>>(inw, inw_b, L_N * 1024 * 256);
    cvt_bf16_kernel<<<dim3(L_N * 80 * 512 / 256), blk, 0, stream>>>(xpw, xpw_b, L_N * 80 * 512);
    cvt_bf16_kernel<<<dim3(L_N * 256 * 512 / 256), blk, 0, stream>>>(outw, outw_b, L_N * 256 * 512);

    // feature extract: pre = x @ fe_w^T + fe_b ; h = relu(LN(pre))
    gemm_bt_kernel<1,0,0><<<dim3(NTOK/64, DM_/64), blk, 0, stream>>>(
        x, INDIM, fe_w, fe_b, pre, DM_, DM_, INDIM);
    ln_relu_kernel<<<dim3(NTOK), blk, 0, stream>>>(pre, ln_g, ln_b, h);

    for (int l = 0; l < L_N; ++l) {
        const ushort* inw_l  = inw_b  + (size_t)l * 2 * DI_ * DM_;
        const ushort* xpw_l  = xpw_b  + (size_t)l * 80 * DI_;
        const float*  dtw_l  = dtw    + (size_t)l * DI_ * DTR_;
        const ushort* outw_l = outw_b + (size_t)l * DM_ * DI_;

        for (int b0 = 0; b0 < B_N; b0 += nb) {
            float* h_c = h + (size_t)b0 * 1024 * DM_;
            // u_b = bf16(rmsnorm(h_c) * blk_norm_g[l])
            rmsnorm_kernel<1><<<dim3(ntok_c), blk, 0, stream>>>(h_c, bng + l * DM_, u_b);
            // xz = u @ inw^T  (single N=1024 MFMA dispatch: x_in | z)
            gemm_mfma_kernel<0><<<dim3(ntok_c/128, (2*DI_)/128), blk, 0, stream>>>(
                u_b, inw_l, xz, 2*DI_, 2*DI_, DM_);
            // xc (f32) + xcb (bf16) = silu(causal_conv(xz[:, :DI]) + cb)
            conv_silu_kernel<<<dim3((ntok_c * DI_) / 256), blk, 0, stream>>>(
                xz, convw + l * DI_ * DC_, convb + l * DI_, xc, xcb);
            // x_dbl = xcb @ xpw^T  (bf16 MFMA, N=80 masked; overlays u_b)
            gemm_mfma_kernel<0><<<dim3(ntok_c/128, 1), blk, 0, stream>>>(
                xcb, xpw_l, xdbl, 80, 80, DI_);
            // delta = softplus(x_dbl[:, :16] @ dtw^T + dtb)  (f32, K=16)
            gemm_bt_kernel<1,1,0><<<dim3(ntok_c/64, DI_/64), blk, 0, stream>>>(
                xdbl, 80, dtw_l, dtb + l * DI_, dlt, DI_, DI_, DTR_);
            // chunk-parallel scan
            scan_passA<<<dim3(nb * 8, NC_), blk, 0, stream>>>(
                xdbl, dlt, xc, alog + (size_t)l * DI_ * DS_, alpha + l, beta + l,
                agg, nstates);
            scan_passB<<<dim3((nstates + 255) / 256), blk, 0, stream>>>(
                agg, st, beta + l, nstates);
            scan_passC<<<dim3(nb * 8, NC_), blk, 0, stream>>>(
                xdbl, dlt, xc, xz + DI_, st, alog + (size_t)l * DI_ * DS_,
                dskip + l * DI_, alpha + l, beta + l, y_b, nstates);
            // h_c += y @ outw^T  (bf16 MFMA, accumulate)
            gemm_mfma_kernel<1><<<dim3(ntok_c/128, DM_/128), blk, 0, stream>>>(
                y_b, outw_l, h_c, DM_, DM_, DI_);
        }
    }

    // out = rmsnorm(h) * rms_g   (in place over d_out)
    rmsnorm_kernel<0><<<dim3(NTOK), blk, 0, stream>>>(h, rmsg, (float*)d_out);
}